// Round 1
// baseline (3091.832 us; speedup 1.0000x reference)
//
#include <hip/hip_runtime.h>

typedef unsigned int u32;
typedef _Float16 h1;
typedef _Float16 h2 __attribute__((ext_vector_type(2)));
typedef _Float16 h8 __attribute__((ext_vector_type(8)));

// Problem dims
// B=512, T-1=63, N=512, H=256, 4H=1024

#define OFF_IE (512*63*512)
#define OFF_W  (512*63*512 + 512*63*256)

// Workspace layout (bytes):
//   t2 half [512][63][512]          @ 0          (33,030,144 B)
//   WihP u32 [256 n2][1024 k]       @ 33,030,144 (1,048,576 B)
//   WhhP u32 [128 j2][1024 k]       @ 34,078,720 (  524,288 B)
//   WcH  half [63][512]             @ 34,603,008 (   64,512 B)
//   bias f32 [1024]                 @ 34,667,520 (    4,096 B)

__device__ __forceinline__ float tanh_fast(float x){
    // tanh(x) = 1 - 2/(exp2(2*log2e*x)+1); saturates correctly at +-inf
    float e = __builtin_amdgcn_exp2f(x * 2.885390081777927f);
    return 1.0f - 2.0f * __builtin_amdgcn_rcpf(e + 1.0f);
}
__device__ __forceinline__ float sigmoid_fast(float x){
    float e = __builtin_amdgcn_exp2f(x * -1.4426950408889634f);
    return __builtin_amdgcn_rcpf(1.0f + e);
}
__device__ __forceinline__ float exp_fast(float x){
    return __builtin_amdgcn_exp2f(x * 1.4426950408889634f);
}
__device__ __forceinline__ float dot2h(u32 a, u32 w, float c){
    return __builtin_amdgcn_fdot2(__builtin_bit_cast(h2, a),
                                  __builtin_bit_cast(h2, w), c, false);
}

__global__ __launch_bounds__(256)
void prep_pack(const float* __restrict__ Wih, const float* __restrict__ Whh,
               const float* __restrict__ bih, const float* __restrict__ bhh,
               const float* __restrict__ Wc,
               u32* __restrict__ WihP, u32* __restrict__ WhhP,
               h1* __restrict__ WcH, float* __restrict__ biasg)
{
    int i = blockIdx.x*256 + threadIdx.x;
    if (i < 262144){                       // W_ih [1024][512] -> [n2][k] half2
        int k = i >> 8, n2 = i & 255;
        float2 w = *(const float2*)(Wih + (size_t)k*512 + 2*n2);
        h2 p; p[0] = (h1)w.x; p[1] = (h1)w.y;
        WihP[n2*1024 + k] = __builtin_bit_cast(u32, p);
    } else if (i < 393216){                // W_hh [1024][256] -> [j2][k] half2
        int j = i - 262144;
        int k = j >> 7, j2 = j & 127;
        float2 w = *(const float2*)(Whh + (size_t)k*256 + 2*j2);
        h2 p; p[0] = (h1)w.x; p[1] = (h1)w.y;
        WhhP[j2*1024 + k] = __builtin_bit_cast(u32, p);
    } else if (i < 425472){                // Wc -> half copy
        int j = i - 393216;
        WcH[j] = (h1)Wc[j];
    } else if (i < 426496){                // bias = b_ih + b_hh
        int k = i - 425472;
        biasg[k] = bih[k] + bhh[k];
    }
}

__global__ __launch_bounds__(256)
void prep_t2(const float* __restrict__ inp, const float* __restrict__ Wd,
             const float* __restrict__ bd, h1* __restrict__ t2)
{
    __shared__ float wd_s[63*63];
    __shared__ float bd_s[63];
    int tid = threadIdx.x;
    for (int i = tid; i < 3969; i += 256) wd_s[i] = Wd[i];
    if (tid < 63) bd_s[tid] = bd[tid];
    __syncthreads();
    int bb = blockIdx.x;                 // batch
    int n  = blockIdx.y*256 + tid;       // input-feature
    float x[63];
    const float* ip = inp + (size_t)bb*63*512 + n;
    #pragma unroll
    for (int t = 0; t < 63; ++t) x[t] = ip[(size_t)t*512];
    h1* op = t2 + (size_t)bb*63*512 + n;
    for (int s = 0; s < 63; ++s){
        float acc = bd_s[s];
        const float* w = wd_s + s*63;
        #pragma unroll
        for (int t = 0; t < 63; ++t) acc = fmaf(x[t], w[t], acc);
        op[(size_t)s*512] = (h1)acc;
    }
}

__global__ __launch_bounds__(512)
void encoder_main(const float* __restrict__ inp, const float* __restrict__ bc,
                  const float* __restrict__ Wa, const float* __restrict__ ba,
                  const h1* __restrict__ t2, const u32* __restrict__ WihP,
                  const u32* __restrict__ WhhP, const h1* __restrict__ WcH,
                  const float* __restrict__ biasg, float* __restrict__ out)
{
    __shared__ float hs[2][512];      // [b][ h(0:256) | c(256:512) ]  fp32 state
    __shared__ u32   hp[2][128];      // packed half2 of h (for dot2)
    __shared__ u32   wxp[2][256];     // packed half2 of wx
    __shared__ float t1s[2][63];
    __shared__ float gates[2][1024];
    __shared__ float t1p[126][4];
    __shared__ float red[8];
    __shared__ float waf[63];
    __shared__ float bias_s[1024];

    const int tid = threadIdx.x;
    const int wg  = blockIdx.x;          // 0..255, owns batches 2wg, 2wg+1

    for (int i = tid; i < 1024; i += 512) ((float*)hs)[i] = 0.0f;
    if (tid < 256) ((u32*)hp)[tid] = 0u;
    for (int i = tid; i < 1024; i += 512) bias_s[i] = biasg[i];
    if (tid < 63) waf[tid] = Wa[tid];
    const float ba_v = ba[0];
    __syncthreads();

    const int b  = tid >> 8;             // 0/1: which of the WG's two batches
    const int bG = wg*2 + b;

    for (int t = 0; t < 63; ++t){
        // ---------- phase 1: t1[b][s] = [h|c] . Wc[s] + bc[s]
        if (tid < 504){
            int oi = tid >> 2, sl = tid & 3;
            int pb = (oi >= 63) ? 1 : 0;
            int s  = oi - 63*pb;
            int base = sl*128;
            const float4* hv = (const float4*)(&hs[pb][base]);
            const h8* wv = (const h8*)(WcH + s*512 + base);
            float acc = 0.f;
            #pragma unroll
            for (int i = 0; i < 16; ++i){
                h8 w = wv[i];
                float4 a = hv[2*i], bq = hv[2*i+1];
                acc += a.x*(float)w[0] + a.y*(float)w[1] + a.z*(float)w[2] + a.w*(float)w[3]
                     + bq.x*(float)w[4] + bq.y*(float)w[5] + bq.z*(float)w[6] + bq.w*(float)w[7];
            }
            t1p[oi][sl] = acc;
        }
        __syncthreads();
        if (tid < 126){
            int pb = (tid >= 63) ? 1 : 0;
            int s  = tid - 63*pb;
            t1s[pb][s] = bc[s] + t1p[tid][0] + t1p[tid][1] + t1p[tid][2] + t1p[tid][3];
        }
        __syncthreads();

        // ---------- phase 2: scores -> softmax -> wx (each thread: 2 adjacent n)
        int n2 = tid & 255;
        const u32* tp = (const u32*)(t2 + (size_t)bG*63*512) + n2;
        float acc0 = 0.f, acc1 = 0.f;
        #pragma unroll 3
        for (int s = 0; s < 63; ++s){
            h2 v = __builtin_bit_cast(h2, tp[s*256]);
            float tt = t1s[b][s], wa = waf[s];
            acc0 = fmaf(wa, tanh_fast(tt + (float)v[0]), acc0);
            acc1 = fmaf(wa, tanh_fast(tt + (float)v[1]), acc1);
        }
        float e0 = exp_fast(acc0 + ba_v);
        float e1 = exp_fast(acc1 + ba_v);
        float es = e0 + e1;
        #pragma unroll
        for (int off = 32; off > 0; off >>= 1) es += __shfl_xor(es, off, 64);
        if ((tid & 63) == 0) red[tid >> 6] = es;
        __syncthreads();
        float tot  = red[b*4+0] + red[b*4+1] + red[b*4+2] + red[b*4+3];
        float rinv = __builtin_amdgcn_rcpf(tot);
        float at0 = e0*rinv, at1 = e1*rinv;
        float2 xv = *(const float2*)(inp + ((size_t)bG*63 + t)*512 + 2*n2);
        float wx0 = at0*xv.x, wx1 = at1*xv.y;
        {
            float2* po = (float2*)(out + ((size_t)bG*63 + t)*512) + n2;
            *po = make_float2(wx0, wx1);
            float2* pa = (float2*)(out + OFF_W + ((size_t)bG*63 + t)*512) + n2;
            *pa = make_float2(at0, at1);
            h2 p; p[0] = (h1)wx0; p[1] = (h1)wx1;
            wxp[b][n2] = __builtin_bit_cast(u32, p);
        }
        __syncthreads();

        // ---------- phase 3: gates = wx.W_ih^T + h.W_hh^T + bias (thread: k=2tid,2tid+1, both batches)
        {
            float a00=0.f, a01=0.f, a10=0.f, a11=0.f;
            const uint2* wp = (const uint2*)WihP + tid;
            #pragma unroll 4
            for (int j = 0; j < 256; ++j){
                uint2 w = wp[(size_t)j*512];
                u32 x0 = wxp[0][j], x1 = wxp[1][j];
                a00 = dot2h(x0, w.x, a00);
                a01 = dot2h(x0, w.y, a01);
                a10 = dot2h(x1, w.x, a10);
                a11 = dot2h(x1, w.y, a11);
            }
            const uint2* wq = (const uint2*)WhhP + tid;
            #pragma unroll 4
            for (int j = 0; j < 128; ++j){
                uint2 w = wq[(size_t)j*512];
                u32 x0 = hp[0][j], x1 = hp[1][j];
                a00 = dot2h(x0, w.x, a00);
                a01 = dot2h(x0, w.y, a01);
                a10 = dot2h(x1, w.x, a10);
                a11 = dot2h(x1, w.y, a11);
            }
            float b0 = bias_s[2*tid], b1 = bias_s[2*tid+1];
            gates[0][2*tid]   = a00 + b0;
            gates[0][2*tid+1] = a01 + b1;
            gates[1][2*tid]   = a10 + b0;
            gates[1][2*tid+1] = a11 + b1;
        }
        __syncthreads();

        // ---------- phase 4: LSTM pointwise update (thread: one j per batch)
        {
            int j = tid & 255;
            float gi = gates[b][j],     gf = gates[b][j+256];
            float gg = gates[b][j+512], go = gates[b][j+768];
            float iv = sigmoid_fast(gi), fv = sigmoid_fast(gf);
            float gv = tanh_fast(gg),    ov = sigmoid_fast(go);
            float co = hs[b][256+j];
            float cn = fmaf(fv, co, iv*gv);
            float hn = ov * tanh_fast(cn);
            hs[b][j]      = hn;
            hs[b][256+j]  = cn;
            ((h1*)hp)[b*256 + j] = (h1)hn;
            out[OFF_IE + ((size_t)bG*63 + t)*256 + j] = hn;
        }
        __syncthreads();
    }
}

extern "C" void kernel_launch(void* const* d_in, const int* in_sizes, int n_in,
                              void* d_out, int out_size, void* d_ws, size_t ws_size,
                              hipStream_t stream)
{
    const float* inp = (const float*)d_in[0];
    const float* Wih = (const float*)d_in[1];
    const float* Whh = (const float*)d_in[2];
    const float* bih = (const float*)d_in[3];
    const float* bhh = (const float*)d_in[4];
    const float* Wc  = (const float*)d_in[5];
    const float* bc  = (const float*)d_in[6];
    const float* Wd  = (const float*)d_in[7];
    const float* bd  = (const float*)d_in[8];
    const float* Wa  = (const float*)d_in[9];
    const float* ba  = (const float*)d_in[10];
    float* out = (float*)d_out;

    char* ws = (char*)d_ws;
    h1*    t2    = (h1*)ws;
    u32*   WihP  = (u32*)(ws + 33030144);
    u32*   WhhP  = (u32*)(ws + 34078720);
    h1*    WcH   = (h1*)(ws + 34603008);
    float* biasg = (float*)(ws + 34667520);

    prep_pack<<<1666, 256, 0, stream>>>(Wih, Whh, bih, bhh, Wc, WihP, WhhP, WcH, biasg);
    prep_t2<<<dim3(512, 2), 256, 0, stream>>>(inp, Wd, bd, t2);
    encoder_main<<<256, 512, 0, stream>>>(inp, bc, Wa, ba, t2, WihP, WhhP, WcH, biasg, out);
}

// Round 2
// 2126.095 us; speedup vs baseline: 1.4542x; 1.4542x over previous
//
#include <hip/hip_runtime.h>

typedef unsigned int u32;
typedef _Float16 h1;
typedef _Float16 h2 __attribute__((ext_vector_type(2)));

// Problem dims: B=512, T-1=63, N=512, H=256, 4H=1024

#define OFF_IE (512*63*512)
#define OFF_W  (512*63*512 + 512*63*256)

// C2 = 2*log2(e): tanh(x) = 1 - 2/(1 + exp2(C2*x)).
// Wc, bc, t2 are pre-scaled by C2 so phase 2 does exp2(t1c + t2c) directly.
#define C2 2.885390081777927f

// Workspace layout (bytes):
//   t2 half [512][63][512] (pre-scaled) @ 0          (33,030,144)
//   WihP u32 [256 n2][1024 k]           @ 33,030,144 (1,048,576)
//   WhhP u32 [128 j2][1024 k]           @ 34,078,720 (  524,288)
//   WcH  half [63][512]  (x C2)        @ 34,603,008 (   64,512)
//   bias f32 [1024]                    @ 34,667,520 (    4,096)

__device__ __forceinline__ float tanh_fast(float x){
    float e = __builtin_amdgcn_exp2f(x * C2);
    return 1.0f - 2.0f * __builtin_amdgcn_rcpf(e + 1.0f);
}
__device__ __forceinline__ float sigmoid_fast(float x){
    float e = __builtin_amdgcn_exp2f(x * -1.4426950408889634f);
    return __builtin_amdgcn_rcpf(1.0f + e);
}
__device__ __forceinline__ float exp_fast(float x){
    return __builtin_amdgcn_exp2f(x * 1.4426950408889634f);
}
__device__ __forceinline__ float dot2h(u32 a, u32 w, float c){
    return __builtin_amdgcn_fdot2(__builtin_bit_cast(h2, a),
                                  __builtin_bit_cast(h2, w), c, false);
}

__global__ __launch_bounds__(256)
void prep_pack(const float* __restrict__ Wih, const float* __restrict__ Whh,
               const float* __restrict__ bih, const float* __restrict__ bhh,
               const float* __restrict__ Wc,
               u32* __restrict__ WihP, u32* __restrict__ WhhP,
               h1* __restrict__ WcH, float* __restrict__ biasg)
{
    int i = blockIdx.x*256 + threadIdx.x;
    if (i < 262144){                       // W_ih [1024][512] -> [n2][k] half2
        int k = i >> 8, n2 = i & 255;
        float2 w = *(const float2*)(Wih + (size_t)k*512 + 2*n2);
        h2 p; p[0] = (h1)w.x; p[1] = (h1)w.y;
        WihP[n2*1024 + k] = __builtin_bit_cast(u32, p);
    } else if (i < 393216){                // W_hh [1024][256] -> [j2][k] half2
        int j = i - 262144;
        int k = j >> 7, j2 = j & 127;
        float2 w = *(const float2*)(Whh + (size_t)k*256 + 2*j2);
        h2 p; p[0] = (h1)w.x; p[1] = (h1)w.y;
        WhhP[j2*1024 + k] = __builtin_bit_cast(u32, p);
    } else if (i < 425472){                // Wc -> half, scaled by C2
        int j = i - 393216;
        WcH[j] = (h1)(C2 * Wc[j]);
    } else if (i < 426496){                // bias = b_ih + b_hh
        int k = i - 425472;
        biasg[k] = bih[k] + bhh[k];
    }
}

__global__ __launch_bounds__(256)
void prep_t2(const float* __restrict__ inp, const float* __restrict__ Wd,
             const float* __restrict__ bd, h1* __restrict__ t2)
{
    __shared__ float wd_s[63*63];
    __shared__ float bd_s[63];
    int tid = threadIdx.x;
    for (int i = tid; i < 3969; i += 256) wd_s[i] = Wd[i];
    if (tid < 63) bd_s[tid] = bd[tid];
    __syncthreads();
    int bb = blockIdx.x;                 // batch
    int n  = blockIdx.y*256 + tid;       // input-feature
    float x[63];
    const float* ip = inp + (size_t)bb*63*512 + n;
    #pragma unroll
    for (int t = 0; t < 63; ++t) x[t] = ip[(size_t)t*512];
    h1* op = t2 + (size_t)bb*63*512 + n;
    for (int s = 0; s < 63; ++s){
        float acc = bd_s[s];
        const float* w = wd_s + s*63;
        #pragma unroll
        for (int t = 0; t < 63; ++t) acc = fmaf(x[t], w[t], acc);
        op[(size_t)s*512] = (h1)(C2 * acc);   // single rounding, pre-scaled
    }
}

#define DOTQ(X0, X1, W) \
    a00 = dot2h((X0), (W).x, a00); a01 = dot2h((X0), (W).y, a01); \
    a10 = dot2h((X1), (W).x, a10); a11 = dot2h((X1), (W).y, a11);

#define CONSUME8(BUF, XS0, XS1, J0) { \
    uint4 _p0 = *(const uint4*)&(XS0)[(J0)]; \
    uint4 _p1 = *(const uint4*)&(XS0)[(J0)+4]; \
    uint4 _q0 = *(const uint4*)&(XS1)[(J0)]; \
    uint4 _q1 = *(const uint4*)&(XS1)[(J0)+4]; \
    DOTQ(_p0.x, _q0.x, BUF[0]) DOTQ(_p0.y, _q0.y, BUF[1]) \
    DOTQ(_p0.z, _q0.z, BUF[2]) DOTQ(_p0.w, _q0.w, BUF[3]) \
    DOTQ(_p1.x, _q1.x, BUF[4]) DOTQ(_p1.y, _q1.y, BUF[5]) \
    DOTQ(_p1.z, _q1.z, BUF[6]) DOTQ(_p1.w, _q1.w, BUF[7]) }

#define PRE8(BUF, PTR) { \
    _Pragma("unroll") \
    for (int _u = 0; _u < 8; ++_u) BUF[_u] = (PTR)[_u*512]; \
    (PTR) += 8*512; }

__global__ __launch_bounds__(512, 1)
void encoder_main(const float* __restrict__ inp, const float* __restrict__ bc,
                  const float* __restrict__ Wa, const float* __restrict__ ba,
                  const h1* __restrict__ t2g, const u32* __restrict__ WihP,
                  const u32* __restrict__ WhhP, const h1* __restrict__ WcH,
                  const float* __restrict__ biasg, float* __restrict__ out)
{
    // LDS: 135168 + 2048 + 2048 + 512 + 2016 + 8192 + 32 + 256 = 150,272 B
    __shared__ u32   t2l[2][256][66];   // row = (b,n2), word s (stride 66 for banks)
    __shared__ u32   hcp[2][256];       // [0..127]=h packed h2, [128..255]=c packed h2
    __shared__ u32   wxp[2][256];       // wx packed h2
    __shared__ float t1s[2][64];        // t1 (scaled); [63] stays 0
    __shared__ float t1p[126][4];
    __shared__ float gates[2][1024];
    __shared__ float red[8];
    __shared__ float wamL[64];          // -2*Wa[s]; [63]=0

    const int tid = threadIdx.x;
    const int wg  = blockIdx.x;          // 0..255, owns batches 2wg, 2wg+1
    const int n2  = tid & 255;
    const int b   = tid >> 8;
    const int bG  = wg*2 + b;

    // ---- prologue ----
    if (tid < 512){
        hcp[tid >> 8][tid & 255] = 0u;   // h=c=0
    }
    if (tid < 64) wamL[tid] = (tid < 63) ? (-2.0f * Wa[tid]) : 0.0f;
    if (tid < 128) ((float*)t1s)[tid] = 0.0f;
    float2 bv = *(const float2*)&biasg[2*tid];            // this thread's 2 gate biases
    float bcv = 0.0f;
    if (tid < 126){
        int pb = (tid >= 63) ? 1 : 0;
        bcv = C2 * bc[tid - 63*pb];
    }
    // stage t2 (pre-scaled h2 pairs) into LDS, transposed to [b][n2][s]
    {
        const u32* tg = (const u32*)(t2g + (size_t)bG*63*512);
        u32* trw = &t2l[b][n2][0];
        for (int s = 0; s < 63; ++s) trw[s] = tg[s*256 + n2];
        trw[63] = 0u; trw[64] = 0u; trw[65] = 0u;
    }
    float c_reg = 0.0f;                 // this thread's fp32 cell state (j = n2, batch b)
    __syncthreads();

    for (int t = 0; t < 63; ++t){
        // ---------- phase 1: t1[b][s] = C2*([h|c].Wc[s] + bc[s])  (fp16 dot2)
        if (tid < 504){
            int oi = tid >> 2, sl = tid & 3;
            int pb = (oi >= 63) ? 1 : 0;
            int s  = oi - 63*pb;
            const uint4* xv4 = (const uint4*)&hcp[pb][sl*64];
            const uint4* wv4 = (const uint4*)(WcH + s*512 + sl*128);
            float acc = 0.f;
            #pragma unroll
            for (int i = 0; i < 16; ++i){
                uint4 x = xv4[i], w = wv4[i];
                acc = dot2h(x.x, w.x, acc);
                acc = dot2h(x.y, w.y, acc);
                acc = dot2h(x.z, w.z, acc);
                acc = dot2h(x.w, w.w, acc);
            }
            t1p[oi][sl] = acc;
        }
        __syncthreads();
        if (tid < 126){
            int pb = (tid >= 63) ? 1 : 0;
            int s  = tid - 63*pb;
            float4 v = *(const float4*)&t1p[tid][0];
            t1s[pb][s] = bcv + v.x + v.y + v.z + v.w;
        }
        __syncthreads();

        // ---------- phase 2: scores -> softmax -> wx (thread: n = 2n2, 2n2+1)
        float2 xv = *(const float2*)(inp + ((size_t)bG*63 + t)*512 + 2*n2);
        const u32* trow = &t2l[b][n2][0];
        float acc0 = 0.f, acc1 = 0.f;
        #pragma unroll 4
        for (int q = 0; q < 32; ++q){
            uint2 tv = *(const uint2*)(trow + 2*q);
            float2 t1v = *(const float2*)&t1s[b][2*q];
            float2 wv  = *(const float2*)&wamL[2*q];
            h2 va = __builtin_bit_cast(h2, tv.x);
            h2 vb = __builtin_bit_cast(h2, tv.y);
            float r0 = __builtin_amdgcn_rcpf(1.f + __builtin_amdgcn_exp2f(t1v.x + (float)va[0]));
            float r1 = __builtin_amdgcn_rcpf(1.f + __builtin_amdgcn_exp2f(t1v.x + (float)va[1]));
            float r2 = __builtin_amdgcn_rcpf(1.f + __builtin_amdgcn_exp2f(t1v.y + (float)vb[0]));
            float r3 = __builtin_amdgcn_rcpf(1.f + __builtin_amdgcn_exp2f(t1v.y + (float)vb[1]));
            acc0 = fmaf(wv.x, r0, acc0);
            acc1 = fmaf(wv.x, r1, acc1);
            acc0 = fmaf(wv.y, r2, acc0);
            acc1 = fmaf(wv.y, r3, acc1);
        }
        // scores shifted by a batch-constant (dropped Swa) — softmax invariant
        float e0 = exp_fast(acc0);
        float e1 = exp_fast(acc1);
        float es = e0 + e1;
        #pragma unroll
        for (int off = 32; off > 0; off >>= 1) es += __shfl_xor(es, off, 64);
        if ((tid & 63) == 0) red[tid >> 6] = es;
        __syncthreads();
        float tot  = red[b*4+0] + red[b*4+1] + red[b*4+2] + red[b*4+3];
        float rinv = __builtin_amdgcn_rcpf(tot);
        float at0 = e0*rinv, at1 = e1*rinv;
        float wx0 = at0*xv.x, wx1 = at1*xv.y;
        {
            float2* po = (float2*)(out + ((size_t)bG*63 + t)*512) + n2;
            *po = make_float2(wx0, wx1);
            float2* pa = (float2*)(out + OFF_W + ((size_t)bG*63 + t)*512) + n2;
            *pa = make_float2(at0, at1);
            h2 p; p[0] = (h1)wx0; p[1] = (h1)wx1;
            wxp[b][n2] = __builtin_bit_cast(u32, p);
        }
        __syncthreads();

        // ---------- phase 3: gates = wx.W_ih^T + h.W_hh^T + bias
        // thread tid: k = 2tid, 2tid+1, both batches; pipelined weight stream.
        float a00 = 0.f, a01 = 0.f, a10 = 0.f, a11 = 0.f;
        {
            const uint2* wp = (const uint2*)WihP + tid;
            uint2 W0[8], W1[8];
            PRE8(W0, wp)
            PRE8(W1, wp)
            #pragma unroll 1
            for (int jb = 0; jb < 16; ++jb){
                CONSUME8(W0, wxp[0], wxp[1], jb*16)
                PRE8(W0, wp)                    // overfetch past end is in-bounds ws
                CONSUME8(W1, wxp[0], wxp[1], jb*16 + 8)
                PRE8(W1, wp)
            }
        }
        {
            const uint2* wq = (const uint2*)WhhP + tid;
            uint2 W0[8], W1[8];
            PRE8(W0, wq)
            PRE8(W1, wq)
            #pragma unroll 1
            for (int jb = 0; jb < 8; ++jb){
                CONSUME8(W0, hcp[0], hcp[1], jb*16)
                PRE8(W0, wq)
                CONSUME8(W1, hcp[0], hcp[1], jb*16 + 8)
                PRE8(W1, wq)
            }
        }
        *(float2*)&gates[0][2*tid] = make_float2(a00 + bv.x, a01 + bv.y);
        *(float2*)&gates[1][2*tid] = make_float2(a10 + bv.x, a11 + bv.y);
        __syncthreads();

        // ---------- phase 4: LSTM pointwise (thread: j = n2, batch b; c in register)
        {
            int j = n2;
            float gi = gates[b][j],     gf = gates[b][j+256];
            float gg = gates[b][j+512], go = gates[b][j+768];
            float iv = sigmoid_fast(gi), fv = sigmoid_fast(gf);
            float gv = tanh_fast(gg),    ov = sigmoid_fast(go);
            float cn = fmaf(fv, c_reg, iv*gv);
            c_reg = cn;
            float hn = ov * tanh_fast(cn);
            ((h1*)&hcp[b][0])[j]   = (h1)hn;   // h packed (phase 1 + phase 3)
            ((h1*)&hcp[b][128])[j] = (h1)cn;   // c packed (phase 1)
            out[OFF_IE + ((size_t)bG*63 + t)*256 + j] = hn;
        }
        __syncthreads();
    }
}

extern "C" void kernel_launch(void* const* d_in, const int* in_sizes, int n_in,
                              void* d_out, int out_size, void* d_ws, size_t ws_size,
                              hipStream_t stream)
{
    const float* inp = (const float*)d_in[0];
    const float* Wih = (const float*)d_in[1];
    const float* Whh = (const float*)d_in[2];
    const float* bih = (const float*)d_in[3];
    const float* bhh = (const float*)d_in[4];
    const float* Wc  = (const float*)d_in[5];
    const float* bc  = (const float*)d_in[6];
    const float* Wd  = (const float*)d_in[7];
    const float* bd  = (const float*)d_in[8];
    const float* Wa  = (const float*)d_in[9];
    const float* ba  = (const float*)d_in[10];
    float* out = (float*)d_out;

    char* ws = (char*)d_ws;
    h1*    t2    = (h1*)ws;
    u32*   WihP  = (u32*)(ws + 33030144);
    u32*   WhhP  = (u32*)(ws + 34078720);
    h1*    WcH   = (h1*)(ws + 34603008);
    float* biasg = (float*)(ws + 34667520);

    prep_pack<<<1666, 256, 0, stream>>>(Wih, Whh, bih, bhh, Wc, WihP, WhhP, WcH, biasg);
    prep_t2<<<dim3(512, 2), 256, 0, stream>>>(inp, Wd, bd, t2);
    encoder_main<<<256, 512, 0, stream>>>(inp, bc, Wa, ba, t2, WihP, WhhP, WcH, biasg, out);
}